// Round 5
// baseline (64.029 us; speedup 1.0000x reference)
//
#include <hip/hip_runtime.h>

// AdderNet forward: out[n,h,w,f] = sum_{dh,dw,c} |Xpad[n,h+dh,w+dw,c] - F[f,dh,dw,c]|
// N=8, H=W=32, C=32, c_out=64, k=3, pad=1. fp32 in/out.
//
// R7 (= R6 with types fixed, no fdot2): f16 inner math, packed accumulate.
// Per 2 channels: v_pk_add_f16(neg) diff, v_and_b32 abs, v_pk_add_f16 acc
// = 1.5 VALU/elem (was 2). Per-pg f16 accs hold <=27 |diffs| (~24, ulp .016);
// cross-pg / cross-chunk sums in f32. LDS tile f16 -> ds_read_b64.
// Structure unchanged from R5: 512 blocks x 512 thr, wave = filter-octet,
// lane = (f:8, c8:8 chunks of 4 channels), ping-pong LDS batches, DPP
// c-reduction (quad_perm 0xB1/0x4E + row_half_mirror 0x141).

#define BLOCK 512

typedef _Float16 h2 __attribute__((ext_vector_type(2)));

__device__ __forceinline__ h2 pkrtz(float a, float b) {
    return __builtin_bit_cast(h2, __builtin_amdgcn_cvt_pkrtz(a, b));
}

__device__ __forceinline__ h2 habs2(h2 a) {
    unsigned u = __builtin_bit_cast(unsigned, a) & 0x7FFF7FFFu;
    return __builtin_bit_cast(h2, u);
}

template <int CTRL>
__device__ __forceinline__ float dpp_add(float s) {
    int t = __builtin_amdgcn_update_dpp(0, __float_as_int(s), CTRL, 0xf, 0xf, true);
    return s + __int_as_float(t);
}

__global__ __launch_bounds__(512, 4) void adder_fwd(const float* __restrict__ X,
                                                    const float* __restrict__ Fg,
                                                    float* __restrict__ out) {
    __shared__ __align__(16) _Float16 Xs[3 * 18 * 32];  // [row][col 0..17][c], f16

    const int b  = blockIdx.x;          // 512 = n(8) x h(32) x wh(2)
    const int wh = b & 1;
    const int h  = (b >> 1) & 31;
    const int n  = b >> 6;
    const int w0 = wh * 16;
    const int tid = threadIdx.x;

    const int lane = tid & 63;
    const int c8   = lane & 7;          // c-chunk: channels c8*4 .. c8*4+3
    const int f    = lane >> 3;         // 0..7 within the wave's filter octet
    const int wave = __builtin_amdgcn_readfirstlane(tid >> 6);
    const int fid  = wave * 8 + f;      // 0..63

    // ---- filter slice -> packed-f16 registers (9 taps x 2 h2 = 18 VGPRs)
    h2 frA[9], frB[9];
    {
        const float* fp = Fg + (size_t)fid * 288 + c8 * 4;
        #pragma unroll
        for (int t = 0; t < 9; ++t) {
            float4 v = *(const float4*)(fp + t * 32);
            frA[t] = pkrtz(v.x, v.y);
            frB[t] = pkrtz(v.z, v.w);
        }
    }

    // ---- stage X rows h-1..h+1, cols w0-1..w0+16 (zero padded), f32 -> f16
    if (tid < 432) {
        int c4  = tid & 7;
        int t   = tid >> 3;             // 0..53 = row*18 + col
        int col = t % 18;
        int row = t / 18;
        int hr  = h + row - 1;
        int gw  = w0 + col - 1;
        float4 v = make_float4(0.f, 0.f, 0.f, 0.f);
        if ((unsigned)hr < 32u && (unsigned)gw < 32u)
            v = ((const float4*)(X + (((size_t)n * 32 + hr) * 32 + gw) * 32))[c4];
        uint2 pk;
        pk.x = __builtin_bit_cast(unsigned, pkrtz(v.x, v.y));
        pk.y = __builtin_bit_cast(unsigned, pkrtz(v.z, v.w));
        *(uint2*)(Xs + (row * 18 + col) * 32 + c4 * 4) = pk;
    }
    __syncthreads();

    const _Float16* xb = Xs + c8 * 4;
    const size_t obase = (((size_t)n * 32 + h) * 32 + w0) * 64 + fid;

    uint2 xA[6], xB[6];
    h2 hA[4], hB[4];
    const h2 hz = pkrtz(0.f, 0.f);

#define LD(dst, dh, col0)                                                      \
    {                                                                          \
        _Pragma("unroll")                                                      \
        for (int j = 0; j < 6; ++j)                                            \
            dst[j] = *(const uint2*)(xb + ((dh) * 18 + (col0) + j) * 32);      \
    }

#define COMP(xx, t0)                                                           \
    {                                                                          \
        _Pragma("unroll")                                                      \
        for (int dw = 0; dw < 3; ++dw) {                                       \
            const h2 fa = frA[(t0) + dw];                                      \
            const h2 fb = frB[(t0) + dw];                                      \
            _Pragma("unroll")                                                  \
            for (int pp = 0; pp < 4; ++pp) {                                   \
                const h2 xl = __builtin_bit_cast(h2, xx[pp + dw].x);           \
                const h2 xh = __builtin_bit_cast(h2, xx[pp + dw].y);           \
                hA[pp] += habs2(xl - fa);                                      \
                hB[pp] += habs2(xh - fb);                                      \
            }                                                                  \
        }                                                                      \
    }

#define PG(pg, B0, B1, LAST)                                                   \
    {                                                                          \
        _Pragma("unroll")                                                      \
        for (int pp = 0; pp < 4; ++pp) { hA[pp] = hz; hB[pp] = hz; }           \
        LD(B1, 1, (pg) * 4);            /* fetch dh=1 */                       \
        COMP(B0, 0);                    /* compute dh=0 */                     \
        LD(B0, 2, (pg) * 4);            /* fetch dh=2 */                       \
        COMP(B1, 3);                    /* compute dh=1 */                     \
        if (!(LAST)) LD(B1, 0, ((pg) + 1) * 4);  /* next pg's dh=0 */          \
        COMP(B0, 6);                    /* compute dh=2 */                     \
        h2 t0 = hA[0] + hB[0];                                                 \
        h2 t1 = hA[1] + hB[1];                                                 \
        h2 t2 = hA[2] + hB[2];                                                 \
        h2 t3 = hA[3] + hB[3];                                                 \
        float s0 = (float)t0[0] + (float)t0[1];                                \
        float s1 = (float)t1[0] + (float)t1[1];                                \
        float s2 = (float)t2[0] + (float)t2[1];                                \
        float s3 = (float)t3[0] + (float)t3[1];                                \
        s0 = dpp_add<0xB1>(s0);  s1 = dpp_add<0xB1>(s1);                       \
        s2 = dpp_add<0xB1>(s2);  s3 = dpp_add<0xB1>(s3);                       \
        s0 = dpp_add<0x4E>(s0);  s1 = dpp_add<0x4E>(s1);                       \
        s2 = dpp_add<0x4E>(s2);  s3 = dpp_add<0x4E>(s3);                       \
        s0 = dpp_add<0x141>(s0); s1 = dpp_add<0x141>(s1);                      \
        s2 = dpp_add<0x141>(s2); s3 = dpp_add<0x141>(s3);                      \
        if (c8 < 4) {                                                          \
            float v = s0;                                                      \
            if (c8 == 1) v = s1;                                               \
            else if (c8 == 2) v = s2;                                          \
            else if (c8 == 3) v = s3;                                          \
            out[obase + (size_t)((pg) * 4 + c8) * 64] = v;                     \
        }                                                                      \
    }

    LD(xA, 0, 0);                       // preload pg=0, dh=0
    PG(0, xA, xB, 0)
    PG(1, xB, xA, 0)
    PG(2, xA, xB, 0)
    PG(3, xB, xA, 1)

#undef PG
#undef COMP
#undef LD
}

extern "C" void kernel_launch(void* const* d_in, const int* in_sizes, int n_in,
                              void* d_out, int out_size, void* d_ws, size_t ws_size,
                              hipStream_t stream) {
    const float* X = (const float*)d_in[0];
    const float* F = (const float*)d_in[1];
    float* out = (float*)d_out;
    adder_fwd<<<dim3(512), dim3(512), 0, stream>>>(X, F, out);
}

// Round 6
// 62.114 us; speedup vs baseline: 1.0308x; 1.0308x over previous
//
#include <hip/hip_runtime.h>

// AdderNet forward: out[n,h,w,f] = sum_{dh,dw,c} |Xpad[n,h+dh,w+dw,c] - F[f,dh,dw,c]|
// N=8, H=W=32, C=32, c_out=64, k=3, pad=1. fp32.
//
// R8 = R5 (best-measured variant, 62.69 us) re-submitted as an A/A noise
// probe. Evidence through R7: dur_us = 40.3us harness poison-fill (268 MB @
// 83% HBM peak) + ~17-18us fixed overhead + ~5us kernel; three consecutive
// major cycle-count cuts (R5 staging x1/2, R7 fp16 -25% VALU/-50% LDS) moved
// dur_us by <= +-1.3us -> kernel is within ~1us of its 4.4us VALU-issue
// floor and further structural work samples noise.
//
// Structure: 512 blocks x 512 thr; block = (n, h, w-half) x all 64 filters;
// wave = filter-octet, lane = (f:8, c8:8 chunks of 4 channels). Filters
// register-resident (fr[9], 36 VGPR). X tile in LDS, ping-pong register
// batches, DPP c-reduction (quad_perm 0xB1/0x4E + row_half_mirror 0x141).

#define BLOCK 512

template <int CTRL>
__device__ __forceinline__ float dpp_add(float s) {
    int t = __builtin_amdgcn_update_dpp(0, __float_as_int(s), CTRL, 0xf, 0xf, true);
    return s + __int_as_float(t);
}

__global__ __launch_bounds__(512, 4) void adder_fwd(const float* __restrict__ X,
                                                    const float* __restrict__ Fg,
                                                    float* __restrict__ out) {
    __shared__ float Xs[3 * 18 * 32];   // [row 0..2][col 0..17][c 0..31]

    const int b  = blockIdx.x;          // 512 = n(8) x h(32) x wh(2)
    const int wh = b & 1;
    const int h  = (b >> 1) & 31;
    const int n  = b >> 6;
    const int w0 = wh * 16;
    const int tid = threadIdx.x;

    const int lane = tid & 63;
    const int c8   = lane & 7;          // c-chunk: floats c8*4 .. c8*4+3
    const int f    = lane >> 3;         // 0..7 within the wave's filter octet
    const int wave = __builtin_amdgcn_readfirstlane(tid >> 6);
    const int fid  = wave * 8 + f;      // 0..63

    // ---- filter slice -> registers (9 taps x float4 = 36 VGPRs)
    float4 fr[9];
    {
        const float* fp = Fg + (size_t)fid * 288 + c8 * 4;
        #pragma unroll
        for (int t = 0; t < 9; ++t)
            fr[t] = *(const float4*)(fp + t * 32);
    }

    // ---- stage X rows h-1..h+1, cols w0-1..w0+16 (zero padded): 432 float4,
    // single pass over 512 threads.
    if (tid < 432) {
        int c4  = tid & 7;
        int t   = tid >> 3;             // 0..53 = row*18 + col
        int col = t % 18;
        int row = t / 18;
        int hr  = h + row - 1;
        int gw  = w0 + col - 1;
        float4 v = make_float4(0.f, 0.f, 0.f, 0.f);
        if ((unsigned)hr < 32u && (unsigned)gw < 32u)
            v = ((const float4*)(X + (((size_t)n * 32 + hr) * 32 + gw) * 32))[c4];
        ((float4*)(Xs + (row * 18 + col) * 32))[c4] = v;
    }
    __syncthreads();

    const float* xb = Xs + c8 * 4;
    const size_t obase = (((size_t)n * 32 + h) * 32 + w0) * 64 + fid;

    float4 xA[6], xB[6], acc[4];

#define LD(dst, dh, col0)                                                   \
    {                                                                       \
        _Pragma("unroll")                                                   \
        for (int j = 0; j < 6; ++j)                                         \
            dst[j] = *(const float4*)(xb + ((dh) * 18 + (col0) + j) * 32);  \
    }

#define COMP(xx, t0)                                                        \
    {                                                                       \
        _Pragma("unroll")                                                   \
        for (int dw = 0; dw < 3; ++dw) {                                    \
            const float4 fv = fr[(t0) + dw];                                \
            _Pragma("unroll")                                               \
            for (int pp = 0; pp < 4; ++pp) {                                \
                const float4 xv = xx[pp + dw];                              \
                acc[pp].x += fabsf(xv.x - fv.x);                            \
                acc[pp].y += fabsf(xv.y - fv.y);                            \
                acc[pp].z += fabsf(xv.z - fv.z);                            \
                acc[pp].w += fabsf(xv.w - fv.w);                            \
            }                                                               \
        }                                                                   \
    }

#define PG(pg, B0, B1, LAST)                                                \
    {                                                                       \
        _Pragma("unroll")                                                   \
        for (int pp = 0; pp < 4; ++pp)                                      \
            acc[pp] = make_float4(0.f, 0.f, 0.f, 0.f);                      \
        LD(B1, 1, (pg) * 4);            /* fetch dh=1 */                    \
        COMP(B0, 0);                    /* compute dh=0 */                  \
        LD(B0, 2, (pg) * 4);            /* fetch dh=2 */                    \
        COMP(B1, 3);                    /* compute dh=1 */                  \
        if (!(LAST)) LD(B1, 0, ((pg) + 1) * 4);  /* next pg's dh=0 */       \
        COMP(B0, 6);                    /* compute dh=2 */                  \
        float s0 = (acc[0].x + acc[0].y) + (acc[0].z + acc[0].w);           \
        float s1 = (acc[1].x + acc[1].y) + (acc[1].z + acc[1].w);           \
        float s2 = (acc[2].x + acc[2].y) + (acc[2].z + acc[2].w);           \
        float s3 = (acc[3].x + acc[3].y) + (acc[3].z + acc[3].w);           \
        s0 = dpp_add<0xB1>(s0);  s1 = dpp_add<0xB1>(s1);                    \
        s2 = dpp_add<0xB1>(s2);  s3 = dpp_add<0xB1>(s3);                    \
        s0 = dpp_add<0x4E>(s0);  s1 = dpp_add<0x4E>(s1);                    \
        s2 = dpp_add<0x4E>(s2);  s3 = dpp_add<0x4E>(s3);                    \
        s0 = dpp_add<0x141>(s0); s1 = dpp_add<0x141>(s1);                   \
        s2 = dpp_add<0x141>(s2); s3 = dpp_add<0x141>(s3);                   \
        if (c8 < 4) {                                                       \
            float v = s0;                                                   \
            if (c8 == 1) v = s1;                                            \
            else if (c8 == 2) v = s2;                                       \
            else if (c8 == 3) v = s3;                                       \
            out[obase + (size_t)((pg) * 4 + c8) * 64] = v;                  \
        }                                                                   \
    }

    LD(xA, 0, 0);                       // preload pg=0, dh=0
    PG(0, xA, xB, 0)
    PG(1, xB, xA, 0)
    PG(2, xA, xB, 0)
    PG(3, xB, xA, 1)

#undef PG
#undef COMP
#undef LD
}

extern "C" void kernel_launch(void* const* d_in, const int* in_sizes, int n_in,
                              void* d_out, int out_size, void* d_ws, size_t ws_size,
                              hipStream_t stream) {
    const float* X = (const float*)d_in[0];
    const float* F = (const float*)d_in[1];
    float* out = (float*)d_out;
    adder_fwd<<<dim3(512), dim3(512), 0, stream>>>(X, F, out);
}